// Round 1
// baseline (200.312 us; speedup 1.0000x reference)
//
#include <hip/hip_runtime.h>
#include <hip/hip_bf16.h>

#define IS 256
#define NEARV 0.1f
#define FARV 100.0f
#define SLICES 8

// ---------------- kernel 1: vertex transform ----------------
// look_at reduces to v - eye (R == I exactly in fp32 for this camera),
// perspective: x/(z*width), y/(z*width). Also precompute 1/max(z,1e-4).
__global__ void kv_transform(const float* __restrict__ verts, float4* __restrict__ vout,
                             int* __restrict__ cnt, int nv) {
    int i = blockIdx.x * 256 + threadIdx.x;
    if (i == 0) *cnt = 0;  // zero the face counter for kernel 2 (ws is poisoned each call)
    if (i >= nv) return;
    float vx = verts[i * 3 + 0];
    float vy = verts[i * 3 + 1];
    float vz = verts[i * 3 + 2];
    float z = vz + 2.7320508075688772f;        // v - eye, eye_z = -(1/tan30 + 1)
    float zs = (fabsf(z) < 1e-5f) ? 1e-5f : z;
    float den = zs * 0.57735026918962576f;     // zs * tan(30 deg)
    float sx = vx / den;
    float sy = vy / den;
    float zc = fmaxf(z, 1e-4f);
    float izc = 1.0f / zc;
    vout[i] = make_float4(sx, sy, z, izc);
}

// ---------------- kernel 2: face gather + cull + compact ----------------
// Per-face data (16 floats): x0,y0,x1,y1 | x2,y2,inv_area,iz0 | iz1,iz2,0,0 | xmin,ymin,xmax,ymax
__global__ void kf_faces(const int* __restrict__ faces, const float4* __restrict__ v,
                         float* __restrict__ fd, int* __restrict__ cnt, int nf) {
    int f = blockIdx.x * 256 + threadIdx.x;
    if (f >= nf) return;
    int i0 = faces[f * 3 + 0];
    int i1 = faces[f * 3 + 1];
    int i2 = faces[f * 3 + 2];
    float4 a = v[i0];
    float4 b = v[i1];
    float4 c = v[i2];
    // front test on view-space z (before any clamp), matching ref: all z > NEAR
    bool front = (a.z > NEARV) && (b.z > NEARV) && (c.z > NEARV);
    float area = (b.x - a.x) * (c.y - a.y) - (c.x - a.x) * (b.y - a.y);
    if (!front || !(fabsf(area) > 1e-8f)) return;  // contributes only FAR -> cull
    float xmin = fminf(a.x, fminf(b.x, c.x));
    float xmax = fmaxf(a.x, fmaxf(b.x, c.x));
    float ymin = fminf(a.y, fminf(b.y, c.y));
    float ymax = fmaxf(a.y, fmaxf(b.y, c.y));
    // screen cull: pixel centers span [-255/256, 255/256]
    const float PMAX = 255.0f / 256.0f;
    if (xmin > PMAX || xmax < -PMAX || ymin > PMAX || ymax < -PMAX) return;
    float ia = 1.0f / area;  // |area| > 1e-8 so area_s == area
    int k = atomicAdd(cnt, 1);
    float4* o = (float4*)(fd + (size_t)k * 16);
    o[0] = make_float4(a.x, a.y, b.x, b.y);
    o[1] = make_float4(c.x, c.y, ia, a.w);
    o[2] = make_float4(b.w, c.w, 0.0f, 0.0f);
    o[3] = make_float4(xmin, ymin, xmax, ymax);
}

// ---------------- kernel 3: clear z-buffer (uint bits of max inv_z, 0 = empty) ----
__global__ void kclear(unsigned int* __restrict__ zb) {
    zb[blockIdx.x * 256 + threadIdx.x] = 0u;
}

// ---------------- kernel 4: tiled raster ----------------
// Grid: (16,16,SLICES) tiles of 16x16 pixels; each z-slice handles a contiguous
// face range. Per chunk of 256 faces: bbox-test vs tile, compact survivors into
// LDS, then every pixel-thread evaluates the compacted list. Track max(inv_zc)
// (== min depth) in a register; one atomicMax per pixel per slice at the end.
__launch_bounds__(256)
__global__ void kr_raster(const float* __restrict__ fd, const int* __restrict__ cnt,
                          unsigned int* __restrict__ zb) {
    __shared__ float sf[256 * 12];
    __shared__ int scount;
    const int tid = threadIdx.x;
    const int tx = tid & 15;
    const int ty = tid >> 4;
    const int j = blockIdx.x * 16 + tx;
    const int i = blockIdx.y * 16 + ty;
    // pixel centers: (2*idx + 1 - 256)/256  (exact in fp32)
    const float px = ((float)(2 * j + 1) - 256.0f) * (1.0f / 256.0f);
    const float py = ((float)(2 * i + 1) - 256.0f) * (1.0f / 256.0f);
    const float px_lo = ((float)(2 * (blockIdx.x * 16) + 1) - 256.0f) * (1.0f / 256.0f);
    const float px_hi = px_lo + 30.0f / 256.0f;
    const float py_lo = ((float)(2 * (blockIdx.y * 16) + 1) - 256.0f) * (1.0f / 256.0f);
    const float py_hi = py_lo + 30.0f / 256.0f;

    const int nf = *cnt;
    const int per = (nf + SLICES - 1) / SLICES;
    const int f0 = blockIdx.z * per;
    const int f1 = min(nf, f0 + per);

    float maxinv = 0.0f;

    for (int base = f0; base < f1; base += 256) {
        if (tid == 0) scount = 0;
        __syncthreads();
        int f = base + tid;
        if (f < f1) {
            const float4* p = (const float4*)(fd + (size_t)f * 16);
            float4 bb = p[3];
            if (bb.x <= px_hi && bb.z >= px_lo && bb.y <= py_hi && bb.w >= py_lo) {
                float4 d0 = p[0];
                float4 d1 = p[1];
                float4 d2 = p[2];
                int k = atomicAdd(&scount, 1);
                float4* q = (float4*)(sf + k * 12);  // 48B stride, 16B aligned
                q[0] = d0;
                q[1] = d1;
                q[2] = d2;
            }
        }
        __syncthreads();
        const int m = scount;
        for (int k = 0; k < m; ++k) {
            const float* q = sf + k * 12;  // all lanes same address -> LDS broadcast
            float x0 = q[0], y0 = q[1], x1 = q[2], y1 = q[3];
            float x2 = q[4], y2 = q[5], ia = q[6];
            float iz0 = q[7], iz1 = q[8], iz2 = q[9];
            float dx0 = x0 - px, dx1 = x1 - px, dx2 = x2 - px;
            float dy0 = y0 - py, dy1 = y1 - py, dy2 = y2 - py;
            float e0 = dx1 * dy2 - dx2 * dy1;
            float e1 = dx2 * dy0 - dx0 * dy2;
            float w0 = e0 * ia;
            float w1 = e1 * ia;
            float w2 = 1.0f - w0 - w1;
            float invz = w0 * iz0 + w1 * iz1 + w2 * iz2;
            float invzc = fmaxf(invz, 1e-6f);
            // zp = 1/invzc; valid iff inside && NEAR < zp < FAR  <=>  0.01 < invzc < 10
            bool ok = (w0 >= 0.0f) && (w1 >= 0.0f) && (w2 >= 0.0f) &&
                      (invzc < 10.0f) && (invzc > 0.01f);
            if (ok) maxinv = fmaxf(maxinv, invzc);
        }
        __syncthreads();
    }
    if (maxinv > 0.0f) atomicMax(&zb[i * IS + j], __float_as_uint(maxinv));
}

// ---------------- kernel 5: bits -> depth, in place ----------------
__global__ void kfin(unsigned int* __restrict__ zb, float* __restrict__ out) {
    int p = blockIdx.x * 256 + threadIdx.x;
    unsigned int m = zb[p];
    out[p] = (m != 0u) ? (1.0f / __uint_as_float(m)) : FARV;
}

extern "C" void kernel_launch(void* const* d_in, const int* in_sizes, int n_in,
                              void* d_out, int out_size, void* d_ws, size_t ws_size,
                              hipStream_t stream) {
    const float* verts = (const float*)d_in[0];
    const int* faces = (const int*)d_in[1];
    float* out = (float*)d_out;
    unsigned int* zb = (unsigned int*)d_out;  // aliased: uint z-bits, converted in place

    const int nv = in_sizes[0] / 3;  // 2502
    const int nf = in_sizes[1] / 3;  // 5000

    char* ws = (char*)d_ws;
    int* cnt = (int*)ws;                               // @0
    float4* vtx = (float4*)(ws + 256);                 // nv * 16 B
    size_t fd_off = 256 + (((size_t)nv * 16 + 255) & ~(size_t)255);
    float* fd = (float*)(ws + fd_off);                 // nf * 64 B

    kv_transform<<<(nv + 255) / 256, 256, 0, stream>>>(verts, vtx, cnt, nv);
    kf_faces<<<(nf + 255) / 256, 256, 0, stream>>>(faces, vtx, fd, cnt, nf);
    kclear<<<(IS * IS) / 256, 256, 0, stream>>>(zb);
    kr_raster<<<dim3(16, 16, SLICES), 256, 0, stream>>>(fd, cnt, zb);
    kfin<<<(IS * IS) / 256, 256, 0, stream>>>(zb, out);
}

// Round 2
// 112.183 us; speedup vs baseline: 1.7856x; 1.7856x over previous
//
#include <hip/hip_runtime.h>
#include <hip/hip_bf16.h>

#define IS 256
#define NEARV 0.1f
#define FARV 100.0f
#define SLICES 32

// ---------------- kernel 1: vertex transform + z-buffer clear ----------------
// look_at reduces to v - eye (R == I exactly in fp32 for this camera),
// perspective: x/(z*width), y/(z*width). Also precompute 1/max(z,1e-4).
// Grid covers IS*IS threads; thread i also clears zb[i].
__global__ void kv_transform(const float* __restrict__ verts, float4* __restrict__ vout,
                             int* __restrict__ cnt, unsigned int* __restrict__ zb, int nv) {
    int i = blockIdx.x * 256 + threadIdx.x;
    if (i == 0) *cnt = 0;  // zero the face counter for kernel 2 (ws is poisoned each call)
    zb[i] = 0u;            // grid == IS*IS exactly
    if (i >= nv) return;
    float vx = verts[i * 3 + 0];
    float vy = verts[i * 3 + 1];
    float vz = verts[i * 3 + 2];
    float z = vz + 2.7320508075688772f;        // v - eye, eye_z = -(1/tan30 + 1)
    float zs = (fabsf(z) < 1e-5f) ? 1e-5f : z;
    float den = zs * 0.57735026918962576f;     // zs * tan(30 deg)
    float sx = vx / den;
    float sy = vy / den;
    float zc = fmaxf(z, 1e-4f);
    float izc = 1.0f / zc;
    vout[i] = make_float4(sx, sy, z, izc);
}

// ---------------- kernel 2: face gather + cull + compact ----------------
// Per-face data (16 floats): x0,y0,x1,y1 | x2,y2,inv_area,iz0 | iz1,iz2,0,0 | xmin,ymin,xmax,ymax
__global__ void kf_faces(const int* __restrict__ faces, const float4* __restrict__ v,
                         float* __restrict__ fd, int* __restrict__ cnt, int nf) {
    int f = blockIdx.x * 256 + threadIdx.x;
    if (f >= nf) return;
    int i0 = faces[f * 3 + 0];
    int i1 = faces[f * 3 + 1];
    int i2 = faces[f * 3 + 2];
    float4 a = v[i0];
    float4 b = v[i1];
    float4 c = v[i2];
    // front test on view-space z (before any clamp), matching ref: all z > NEAR
    bool front = (a.z > NEARV) && (b.z > NEARV) && (c.z > NEARV);
    float area = (b.x - a.x) * (c.y - a.y) - (c.x - a.x) * (b.y - a.y);
    if (!front || !(fabsf(area) > 1e-8f)) return;  // contributes only FAR -> cull
    float xmin = fminf(a.x, fminf(b.x, c.x));
    float xmax = fmaxf(a.x, fmaxf(b.x, c.x));
    float ymin = fminf(a.y, fminf(b.y, c.y));
    float ymax = fmaxf(a.y, fmaxf(b.y, c.y));
    // screen cull: pixel centers span [-255/256, 255/256]
    const float PMAX = 255.0f / 256.0f;
    if (xmin > PMAX || xmax < -PMAX || ymin > PMAX || ymax < -PMAX) return;
    float ia = 1.0f / area;  // |area| > 1e-8 so area_s == area
    int k = atomicAdd(cnt, 1);
    float4* o = (float4*)(fd + (size_t)k * 16);
    o[0] = make_float4(a.x, a.y, b.x, b.y);
    o[1] = make_float4(c.x, c.y, ia, a.w);
    o[2] = make_float4(b.w, c.w, 0.0f, 0.0f);
    o[3] = make_float4(xmin, ymin, xmax, ymax);
}

// ---------------- kernel 3: tiled raster ----------------
// Grid: (16,16,SLICES) tiles of 16x16 pixels; each z-slice handles a contiguous
// face range (~nf/SLICES faces, <= 256 so the chunk loop runs once). Per chunk:
// bbox-test vs tile, compact survivors into LDS, then every pixel-thread
// evaluates the compacted list with ds_read_b128 broadcasts. Track max(inv_zc)
// (== min depth) in a register; one atomicMax per covered pixel at the end.
__launch_bounds__(256)
__global__ void kr_raster(const float* __restrict__ fd, const int* __restrict__ cnt,
                          unsigned int* __restrict__ zb) {
    __shared__ float sf[256 * 12];
    __shared__ int scount;
    const int tid = threadIdx.x;
    const int tx = tid & 15;
    const int ty = tid >> 4;
    const int j = blockIdx.x * 16 + tx;
    const int i = blockIdx.y * 16 + ty;
    // pixel centers: (2*idx + 1 - 256)/256  (exact in fp32)
    const float px = ((float)(2 * j + 1) - 256.0f) * (1.0f / 256.0f);
    const float py = ((float)(2 * i + 1) - 256.0f) * (1.0f / 256.0f);
    const float px_lo = ((float)(2 * (blockIdx.x * 16) + 1) - 256.0f) * (1.0f / 256.0f);
    const float px_hi = px_lo + 30.0f / 256.0f;
    const float py_lo = ((float)(2 * (blockIdx.y * 16) + 1) - 256.0f) * (1.0f / 256.0f);
    const float py_hi = py_lo + 30.0f / 256.0f;

    const int nf = *cnt;
    const int per = (nf + SLICES - 1) / SLICES;
    const int f0 = blockIdx.z * per;
    const int f1 = min(nf, f0 + per);

    float maxinv = 0.0f;

    for (int base = f0; base < f1; base += 256) {
        if (tid == 0) scount = 0;
        __syncthreads();
        int f = base + tid;
        if (f < f1) {
            const float4* p = (const float4*)(fd + (size_t)f * 16);
            float4 bb = p[3];
            if (bb.x <= px_hi && bb.z >= px_lo && bb.y <= py_hi && bb.w >= py_lo) {
                float4 d0 = p[0];
                float4 d1 = p[1];
                float4 d2 = p[2];
                int k = atomicAdd(&scount, 1);
                float4* q = (float4*)(sf + k * 12);  // 48B stride, 16B aligned
                q[0] = d0;
                q[1] = d1;
                q[2] = d2;
            }
        }
        __syncthreads();
        const int m = scount;
#pragma unroll 2
        for (int k = 0; k < m; ++k) {
            const float4* q = (const float4*)(sf + k * 12);  // uniform addr -> LDS broadcast
            float4 d0 = q[0];
            float4 d1 = q[1];
            float4 d2 = q[2];
            float x0 = d0.x, y0 = d0.y, x1 = d0.z, y1 = d0.w;
            float x2 = d1.x, y2 = d1.y, ia = d1.z;
            float iz0 = d1.w, iz1 = d2.x, iz2 = d2.y;
            float dx0 = x0 - px, dx1 = x1 - px, dx2 = x2 - px;
            float dy0 = y0 - py, dy1 = y1 - py, dy2 = y2 - py;
            float e0 = dx1 * dy2 - dx2 * dy1;
            float e1 = dx2 * dy0 - dx0 * dy2;
            float w0 = e0 * ia;
            float w1 = e1 * ia;
            float w2 = 1.0f - w0 - w1;
            float invz = w0 * iz0 + w1 * iz1 + w2 * iz2;
            float invzc = fmaxf(invz, 1e-6f);
            // zp = 1/invzc; valid iff inside && NEAR < zp < FAR  <=>  0.01 < invzc < 10
            bool ok = (w0 >= 0.0f) && (w1 >= 0.0f) && (w2 >= 0.0f) &&
                      (invzc < 10.0f) && (invzc > 0.01f);
            if (ok) maxinv = fmaxf(maxinv, invzc);
        }
        __syncthreads();
    }
    if (maxinv > 0.0f) atomicMax(&zb[i * IS + j], __float_as_uint(maxinv));
}

// ---------------- kernel 4: bits -> depth, in place ----------------
__global__ void kfin(unsigned int* __restrict__ zb, float* __restrict__ out) {
    int p = blockIdx.x * 256 + threadIdx.x;
    unsigned int m = zb[p];
    out[p] = (m != 0u) ? (1.0f / __uint_as_float(m)) : FARV;
}

extern "C" void kernel_launch(void* const* d_in, const int* in_sizes, int n_in,
                              void* d_out, int out_size, void* d_ws, size_t ws_size,
                              hipStream_t stream) {
    const float* verts = (const float*)d_in[0];
    const int* faces = (const int*)d_in[1];
    float* out = (float*)d_out;
    unsigned int* zb = (unsigned int*)d_out;  // aliased: uint z-bits, converted in place

    const int nv = in_sizes[0] / 3;  // 2502
    const int nf = in_sizes[1] / 3;  // 5000

    char* ws = (char*)d_ws;
    int* cnt = (int*)ws;                               // @0
    float4* vtx = (float4*)(ws + 256);                 // nv * 16 B
    size_t fd_off = 256 + (((size_t)nv * 16 + 255) & ~(size_t)255);
    float* fd = (float*)(ws + fd_off);                 // nf * 64 B

    kv_transform<<<(IS * IS) / 256, 256, 0, stream>>>(verts, vtx, cnt, zb, nv);
    kf_faces<<<(nf + 255) / 256, 256, 0, stream>>>(faces, vtx, fd, cnt, nf);
    kr_raster<<<dim3(16, 16, SLICES), 256, 0, stream>>>(fd, cnt, zb);
    kfin<<<(IS * IS) / 256, 256, 0, stream>>>(zb, out);
}